// Round 16
// baseline (146.747 us; speedup 1.0000x reference)
//
#include <hip/hip_runtime.h>

// LDS forward collapsed to causal conv:
//   y[b,t,o] = sum_{d<=t} x[b,t-d] * K[d,o] + G[t,o]
//   K[d,o] = sum_s C[s,o] A[s]^d B[s]  (+ M[o,0,d-1] for d in 1..5)
//   G[t,o] = sum_s C[s,o] A[s]^{t+1} h0[s]
//
// R16: switch the MFMA shape to 32x32x16 (2x FLOP/instr, 17% cheaper per
// FLOP) and wave = 128t x 32o (mi=4, ni=1). Toeplitz diagonal j = ks - 2*mi
// advances 1 frag per k-step -> 38 ds_read_b128 per 128 MFMAs, and 128t
// waves halve waves-per-area: LDS-pipe cycles per CU-batch drop 3648->1872
// (the R12-measured bottleneck). B-slice bfr[32] = 128 VGPR, acc[4] = 64,
// aw[8] = 32, no staging regs (global_load_lds), no gacc -> ~240 VGPR peak.
// Block = 4 waves (256 thr) = 512t x 32o, NB=8, grid (16 oc, 32 bg) = 512
// blocks = 2/CU (independent barriers -> phase-slide, T5 setprio regime).

typedef __attribute__((ext_vector_type(8))) short short8v;
typedef __attribute__((ext_vector_type(4))) float float4v;
typedef __attribute__((ext_vector_type(16))) float float16v;

#define NB 8

static __device__ __forceinline__ unsigned short f2bf(float f) {
    union { float f; unsigned int u; } x; x.f = f;
    unsigned int r = x.u + 0x7fffu + ((x.u >> 16) & 1u);  // RNE
    return (unsigned short)(r >> 16);
}

// ---------------- prep: KT/G (blocks 0..1023) + XOCT (blocks 1024..1279) ---
__global__ __launch_bounds__(256) void k_prep(const float* __restrict__ A,
                                              const float* __restrict__ B,
                                              const float* __restrict__ h0,
                                              const float* __restrict__ C,
                                              const float* __restrict__ M,
                                              const float* __restrict__ x,
                                              unsigned short* __restrict__ KT,
                                              float* __restrict__ G,
                                              short8v* __restrict__ XOCT) {
    __shared__ float PBL[512][4];
    __shared__ float PHL[512][4];
    __shared__ float red[4][64][8];
    __shared__ unsigned short xs[512];
    const int tid = threadIdx.x;

    if (blockIdx.x < 1024) {
        const int d0 = (blockIdx.x & 127) * 4;
        const int oc = blockIdx.x >> 7;

        #pragma unroll
        for (int q = 0; q < 2; ++q) {
            int ss = tid + q * 256;
            float a = A[ss];
            float r = 1.0f, base = a;
            #pragma unroll
            for (int bit = 0; bit < 9; ++bit) {
                if (d0 & (1 << bit)) r *= base;
                base *= base;
            }
            float bs = B[ss], hs = h0[ss];
            #pragma unroll
            for (int j = 0; j < 4; ++j) {
                PBL[ss][j] = r * bs;
                PHL[ss][j] = r * a * hs;
                r *= a;
            }
        }
        __syncthreads();

        const int lane = tid & 63;
        const int sc   = tid >> 6;
        const int o    = oc * 64 + lane;
        float kt[4] = {0.f, 0.f, 0.f, 0.f};
        float gg[4] = {0.f, 0.f, 0.f, 0.f};
        for (int si = 0; si < 128; si += 8) {
            float c8[8];
            #pragma unroll
            for (int u = 0; u < 8; ++u)
                c8[u] = C[(sc * 128 + si + u) * 512 + o];
            #pragma unroll
            for (int u = 0; u < 8; ++u) {
                int s = sc * 128 + si + u;
                #pragma unroll
                for (int j = 0; j < 4; ++j) {
                    kt[j] = fmaf(PBL[s][j], c8[u], kt[j]);
                    gg[j] = fmaf(PHL[s][j], c8[u], gg[j]);
                }
            }
        }
        #pragma unroll
        for (int j = 0; j < 4; ++j) {
            red[sc][lane][j]     = kt[j];
            red[sc][lane][j + 4] = gg[j];
        }
        __syncthreads();
        if (sc == 0) {
            #pragma unroll
            for (int j = 0; j < 4; ++j) {
                float v  = red[0][lane][j] + red[1][lane][j]
                         + red[2][lane][j] + red[3][lane][j];
                float gv = red[0][lane][j+4] + red[1][lane][j+4]
                         + red[2][lane][j+4] + red[3][lane][j+4];
                int d = d0 + j;
                if (d >= 1 && d <= 5) v += M[o * 5 + (d - 1)];
                KT[o * 512 + d] = f2bf(v);
                G[d * 512 + o]  = gv;
            }
        }
    } else {
        // xprep: unpadded reversed-octet table, 1024 entries per batch
        const int b = blockIdx.x - 1024;
        #pragma unroll
        for (int q = 0; q < 2; ++q) {
            int i = tid * 2 + q;
            xs[i] = f2bf(x[b * 512 + 511 - i]);
        }
        __syncthreads();
        short8v* dst = XOCT + (size_t)b * 1024;
        #pragma unroll
        for (int q = 0; q < 4; ++q) {
            int e = tid * 4 + q;
            short8v v;
            #pragma unroll
            for (int jj = 0; jj < 8; ++jj) {
                int i = e + jj;
                v[jj] = (i < 512) ? (short)xs[i] : (short)0;
            }
            dst[e] = v;
        }
    }
}

// ---------------- main: 512 blocks x 256 thr, 32x32x16 MFMA ----------------
__global__ __launch_bounds__(256, 2) void k_main(const short8v* __restrict__ XOCT,
                                                 const unsigned short* __restrict__ KT,
                                                 const float* __restrict__ G,
                                                 float* __restrict__ out) {
    __shared__ short8v xbuf[2][1024];   // 32 KB, double-buffered octet tables

    const int bo0 = blockIdx.x * 32;    // 16 o-chunks
    const int b0  = blockIdx.y * NB;    // 32 batch-groups
    const int tid  = threadIdx.x;
    const int lane = tid & 63;
    const int wv   = tid >> 6;          // 0..3 -> 128t chunk
    const int t0w  = wv * 128;
    const int r32  = lane & 31;         // row/col within 32
    const int h    = lane >> 5;         // k-half

    // ---- prologue: stage batch 0 + B-slice regs ----
    {
        const short8v* src = XOCT + (size_t)b0 * 1024;
        #pragma unroll
        for (int q = 0; q < 4; ++q) {
            int base = q * 256 + wv * 64;
            __builtin_amdgcn_global_load_lds(
                (const __attribute__((address_space(1))) void*)(src + base + lane),
                (__attribute__((address_space(3))) void*)(&xbuf[0][base]),
                16, 0, 0);
        }
    }

    // B-operand (KT) frags: frag ks covers d in [16ks,16ks+16); lane holds
    // row o = bo0 + r32, d = 16ks + 8h + [0..7]  -> short8v, 128 VGPR.
    short8v bfr[32];
    {
        const unsigned short* bp = KT + (bo0 + r32) * 512 + 8 * h;
        #pragma unroll
        for (int ks = 0; ks < 32; ++ks)
            bfr[ks] = *(const short8v*)(bp + ks * 16);
    }

    asm volatile("s_waitcnt vmcnt(0)" ::: "memory");
    __builtin_amdgcn_s_barrier();

    // Toeplitz A-operand: lane holds col t = t0w + 32mi + r32, k = 16ks+8h+..
    // -> octet entry e = Ew + 16*(ks - 2*mi),  j = ks-2mi in [-6, 31].
    const int Ew = 511 - t0w - r32 + 8 * h;

    int p = 0;
    for (int bi = 0; bi < NB; ++bi) {
        // stage next batch early (oldest in vmcnt order)
        if (bi + 1 < NB) {
            const short8v* src = XOCT + (size_t)(b0 + bi + 1) * 1024;
            short8v* dstb = xbuf[p ^ 1];
            #pragma unroll
            for (int q = 0; q < 4; ++q) {
                int base = q * 256 + wv * 64;
                __builtin_amdgcn_global_load_lds(
                    (const __attribute__((address_space(1))) void*)(src + base + lane),
                    (__attribute__((address_space(3))) void*)(dstb + base),
                    16, 0, 0);
            }
        }

        const short8v* xo = xbuf[p];

        float16v acc[4];
        #pragma unroll
        for (int mi = 0; mi < 4; ++mi) acc[mi] = (float16v)(0.0f);

        // A window: 8 slots, live j in [ks-6, ks+1], refill j=ks+2 at step ks
        short8v aw[8];
        #pragma unroll
        for (int j = -6; j <= 1; ++j)
            aw[j & 7] = xo[Ew + 16 * j];

        __builtin_amdgcn_s_setprio(1);
        #pragma unroll
        for (int ks = 0; ks < 32; ++ks) {
            // mi=3 consumes the oldest slot (j = ks-6), then refill it
            acc[3] = __builtin_amdgcn_mfma_f32_32x32x16_bf16(
                bfr[ks], aw[(ks - 6) & 7], acc[3], 0, 0, 0);
            if (ks < 30)
                aw[(ks + 2) & 7] = xo[Ew + 16 * (ks + 2)];
            acc[2] = __builtin_amdgcn_mfma_f32_32x32x16_bf16(
                bfr[ks], aw[(ks - 4) & 7], acc[2], 0, 0, 0);
            acc[1] = __builtin_amdgcn_mfma_f32_32x32x16_bf16(
                bfr[ks], aw[(ks - 2) & 7], acc[1], 0, 0, 0);
            acc[0] = __builtin_amdgcn_mfma_f32_32x32x16_bf16(
                bfr[ks], aw[ks & 7], acc[0], 0, 0, 0);
        }
        __builtin_amdgcn_s_setprio(0);

        // epilogue: D col=lane&31 -> t, row=(reg&3)+8(reg>>2)+4h -> o.
        // reg-quad q => float4 at o = bo0 + 8q + 4h, t = t0w + 32mi + r32.
        float* op = out + (size_t)(b0 + bi) * 262144;
        #pragma unroll
        for (int mi = 0; mi < 4; ++mi) {
            const int t = t0w + 32 * mi + r32;
            const int base = t * 512 + bo0 + 4 * h;
            #pragma unroll
            for (int q = 0; q < 4; ++q) {
                float4v gv = *(const float4v*)(G + base + 8 * q);
                float4v v = { acc[mi][4*q+0], acc[mi][4*q+1],
                              acc[mi][4*q+2], acc[mi][4*q+3] };
                *(float4v*)(op + base + 8 * q) = v + gv;
            }
        }

        // counted barrier: drains only the 4 stage-glds (oldest of 36);
        // the 16 G-loads are already consumed, 16 stores keep flying.
        if (bi + 1 < NB) {
            asm volatile("s_waitcnt vmcnt(32)" ::: "memory");
            __builtin_amdgcn_s_barrier();
            p ^= 1;
        }
    }
}

extern "C" void kernel_launch(void* const* d_in, const int* in_sizes, int n_in,
                              void* d_out, int out_size, void* d_ws, size_t ws_size,
                              hipStream_t stream) {
    const float* x  = (const float*)d_in[0];   // [256,512,1]
    const float* A  = (const float*)d_in[1];   // [512]
    const float* B  = (const float*)d_in[2];   // [1,512]
    const float* C  = (const float*)d_in[3];   // [512,512]
    const float* M  = (const float*)d_in[4];   // [512,1,5]
    const float* h0 = (const float*)d_in[5];   // [512]
    float* out = (float*)d_out;

    char* ws = (char*)d_ws;
    unsigned short* KT   = (unsigned short*)ws;                      // 512 KB
    float*          G    = (float*)(ws + (1u << 19));                // 1 MB
    short8v*        XOCT = (short8v*)(ws + (1u << 19) + (1u << 20)); // 4 MB

    k_prep<<<1280, 256, 0, stream>>>(A, B, h0, C, M, x, KT, G, XOCT);
    k_main<<<dim3(16, 32), 256, 0, stream>>>(XOCT, KT, G, out);
}